// Round 3
// baseline (240.389 us; speedup 1.0000x reference)
//
#include <hip/hip_runtime.h>
#include <hip/hip_bf16.h>

// B=4, N=128, L=20, D=512
#define Bc 4
#define Nc 128
#define Lc 20
#define Dc 512
#define SCALE 0.04419417382415922f   // 1/sqrt(512)
#define NL2E -1.4426950408889634f    // -log2(e)

#if __has_builtin(__builtin_amdgcn_exp2f)
#define EXP2(x) __builtin_amdgcn_exp2f(x)
#else
#define EXP2(x) __expf((x) * 0.6931471805599453f)
#endif

// ---------------------------------------------------------------------------
// Kernel 1: q/k projections. 32x32 tiles, 2x2 micro-tile, k-major LDS,
// 4-way K-split (blockIdx.z, K=128 each) + register prefetch. 1216 blocks.
// Partial outputs q[kh] / k[kh]; consumers sum the 4 parts.
// ---------------------------------------------------------------------------
__global__ __launch_bounds__(256)
void proj_gemm(const float* __restrict__ f_b, const float* __restrict__ f_w,
               const float* __restrict__ Wq, const float* __restrict__ bq,
               const float* __restrict__ Wk, const float* __restrict__ bk,
               float* __restrict__ qb, float* __restrict__ kb) {
    const int t  = threadIdx.x;
    const int tr = blockIdx.y, tc = blockIdx.x, kh = blockIdx.z;
    const int c0 = tc * 32;
    const bool isq = tr < 16;
    const float* Ain  = isq ? f_b : f_w;
    const float* W    = isq ? Wq : Wk;
    const float* bias = isq ? bq : bk;           // added only in kh==0 part
    float* C          = isq ? (qb + kh * 512 * Dc) : (kb + kh * 80 * Dc);
    const int r0    = isq ? tr * 32 : (tr - 16) * 32;
    const int nrows = isq ? 512 : 80;
    const int kbase = kh * 128;

    __shared__ __align__(16) float As[16 * 34];   // [k][row+pad]
    __shared__ __align__(16) float Bs[16 * 34];

    const int sr  = t >> 3;            // staged row 0..31
    const int sk2 = (t & 7) * 2;       // staged k pair 0..14
    const int arow = min(r0 + sr, nrows - 1);
    const int wrow = c0 + sr;

    const int ty2 = (t >> 4) * 2;      // out row pair
    const int tx2 = (t & 15) * 2;      // out col pair
    float a00 = 0.f, a01 = 0.f, a10 = 0.f, a11 = 0.f;

    const float* Aptr = Ain + arow * Dc + kbase + sk2;
    const float* Wptr = W   + wrow * Dc + kbase + sk2;
    float2 ga = *(const float2*)Aptr;
    float2 gb = *(const float2*)Wptr;

    for (int kk0 = 16; kk0 <= 128; kk0 += 16) {
        __syncthreads();
        As[sk2 * 34 + sr]       = ga.x;
        As[(sk2 + 1) * 34 + sr] = ga.y;
        Bs[sk2 * 34 + sr]       = gb.x;
        Bs[(sk2 + 1) * 34 + sr] = gb.y;
        __syncthreads();
        if (kk0 < 128) {                       // prefetch next tile
            ga = *(const float2*)(Aptr + kk0);
            gb = *(const float2*)(Wptr + kk0);
        }
#pragma unroll
        for (int kk = 0; kk < 16; kk++) {
            const float2 av = *(const float2*)&As[kk * 34 + ty2];
            const float2 bv = *(const float2*)&Bs[kk * 34 + tx2];
            a00 = fmaf(av.x, bv.x, a00); a01 = fmaf(av.x, bv.y, a01);
            a10 = fmaf(av.y, bv.x, a10); a11 = fmaf(av.y, bv.y, a11);
        }
    }
    const int orow = r0 + ty2;
    const float b0 = kh ? 0.f : bias[c0 + tx2];
    const float b1 = kh ? 0.f : bias[c0 + tx2 + 1];
    if (orow < nrows)
        *(float2*)&C[orow * Dc + c0 + tx2] = make_float2(a00 + b0, a01 + b1);
    if (orow + 1 < nrows)
        *(float2*)&C[(orow + 1) * Dc + c0 + tx2] = make_float2(a10 + b0, a11 + b1);
}

// ---------------------------------------------------------------------------
// Kernel 2: cross-attention over L=20 + sentence gate -> f_bq
// (sums the four K-split parts of q and k at load)
// ---------------------------------------------------------------------------
__global__ __launch_bounds__(256)
void cross_attn_gate(const float* __restrict__ qb, const float* __restrict__ kb,
                     const float* __restrict__ f_w, const float* __restrict__ f_b,
                     const float* __restrict__ f_s, float* __restrict__ f_bq) {
    const int bn = blockIdx.x;
    const int b  = bn >> 7;
    const int t  = threadIdx.x;
    const int lane = t & 63, wave = t >> 6;

    __shared__ __align__(16) float qs[Dc];
    __shared__ float sc[32];
    __shared__ float invs;

    {
        float2 s = make_float2(0.f, 0.f);
#pragma unroll
        for (int h = 0; h < 4; h++) {
            const float2 u = ((const float2*)(qb + h * 512 * Dc + bn * Dc))[t];
            s.x += u.x; s.y += u.y;
        }
        ((float2*)qs)[t] = s;
    }
    __syncthreads();

    const float4* q4 = (const float4*)qs;
    const float4 qa = q4[lane];
    const float4 qv = q4[lane + 64];

    for (int l = wave; l < Lc; l += 4) {
        float4 ka = make_float4(0.f, 0.f, 0.f, 0.f);
        float4 kv = make_float4(0.f, 0.f, 0.f, 0.f);
#pragma unroll
        for (int h = 0; h < 4; h++) {
            const float4* kr = (const float4*)(kb + h * 80 * Dc + (b * Lc + l) * Dc);
            const float4 u = kr[lane];
            const float4 v = kr[lane + 64];
            ka.x += u.x; ka.y += u.y; ka.z += u.z; ka.w += u.w;
            kv.x += v.x; kv.y += v.y; kv.z += v.z; kv.w += v.w;
        }
        float s = qa.x * ka.x + qa.y * ka.y + qa.z * ka.z + qa.w * ka.w
                + qv.x * kv.x + qv.y * kv.y + qv.z * kv.z + qv.w * kv.w;
#pragma unroll
        for (int d = 32; d >= 1; d >>= 1) s += __shfl_down(s, d, 64);
        if (lane == 0) sc[l] = s * SCALE;
    }
    __syncthreads();

    if (t == 0) {
        float mx = sc[0];
        for (int l = 1; l < Lc; l++) mx = fmaxf(mx, sc[l]);
        float sum = 0.f;
        for (int l = 0; l < Lc; l++) { float e = __expf(sc[l] - mx); sc[l] = e; sum += e; }
        invs = 1.0f / sum;
    }
    __syncthreads();
    const float inv = invs;

    const float2* fw2 = (const float2*)(f_w + b * Lc * Dc);
    float2 acc = make_float2(0.f, 0.f);
#pragma unroll 5
    for (int l = 0; l < Lc; l++) {
        const float2 v = fw2[l * 256 + t];
        const float w = sc[l];
        acc.x = fmaf(w, v.x, acc.x);
        acc.y = fmaf(w, v.y, acc.y);
    }
    const float2 s2 = ((const float2*)(f_s + b * Dc))[t];
    const float2 fb2 = ((const float2*)(f_b + bn * Dc))[t];
    float2 o;
    o.x = fb2.x * (acc.x * inv + s2.x);
    o.y = fb2.y * (acc.y * inv + s2.y);
    ((float2*)(f_bq + bn * Dc))[t] = o;
}

// ---------------------------------------------------------------------------
// Kernel 3: A_b / A_bT softmax rows. 512 threads (8 waves).
// Reductions over the 128 scores via per-wave shuffle butterflies.
// ---------------------------------------------------------------------------
__global__ __launch_bounds__(512)
void self_attn_scores(const float* __restrict__ f_bq,
                      float* __restrict__ A_b, float* __restrict__ A_bT) {
    const int bn = blockIdx.x;
    const int b  = bn >> 7, n = bn & 127;
    const int t  = threadIdx.x;          // 0..511
    const int lane = t & 63, wave = t >> 6;   // 8 waves

    __shared__ __align__(16) float qrow[Dc];
    __shared__ float sc[Nc];
    __shared__ float redm[2];
    __shared__ float reds[2];

    qrow[t] = f_bq[bn * Dc + t];
    __syncthreads();

    const float4* q4 = (const float4*)qrow;
    const float4 qa = q4[lane];
    const float4 qv = q4[lane + 64];

    for (int m = wave; m < Nc; m += 8) {
        const float4* kr = (const float4*)(f_bq + (b * Nc + m) * Dc);
        const float4 va = kr[lane];
        const float4 vb = kr[lane + 64];
        float s = qa.x * va.x + qa.y * va.y + qa.z * va.z + qa.w * va.w
                + qv.x * vb.x + qv.y * vb.y + qv.z * vb.z + qv.w * vb.w;
#pragma unroll
        for (int d = 32; d >= 1; d >>= 1) s += __shfl_down(s, d, 64);
        if (lane == 0) sc[m] = s * SCALE;
    }
    __syncthreads();

    float sval = 0.f, e = 0.f;
    if (t < Nc) {                         // waves 0 and 1 exactly
        sval = sc[t];
        float m = sval;
#pragma unroll
        for (int d = 32; d >= 1; d >>= 1) m = fmaxf(m, __shfl_xor(m, d, 64));
        if (lane == 0) redm[wave] = m;
    }
    __syncthreads();
    if (t < Nc) {
        const float mx = fmaxf(redm[0], redm[1]);
        e = __expf(sval - mx);
        float s = e;
#pragma unroll
        for (int d = 32; d >= 1; d >>= 1) s += __shfl_xor(s, d, 64);
        if (lane == 0) reds[wave] = s;
    }
    __syncthreads();
    if (t < Nc) {
        const float a = e * (1.0f / (reds[0] + reds[1]));
        A_b[bn * Nc + t] = a;
        A_bT[(b * Nc + t) * Nc + n] = a;
    }
}

// ---------------------------------------------------------------------------
// Kernel 4: fused moment reduction + self-attn apply + residual.
// grid (512, 2): blockIdx.x = (b,j), blockIdx.y = d-HALF (64 float4).
// 256 threads = 64 f4-lanes x 4 i-groups of 32. Each wave load is one
// contiguous 1 KB global_load_dwordx4; 8 f_m loads in flight per batch.
// Changes this round: (a) dropped nontemporal flag on f_m loads (no
// measured upside, possible L2/L3 downside); (b) the A_b @ f_b pass is
// interleaved INTO the f_m batch loop (separate accumulator) so its L2
// reads hide under the HBM stream instead of serializing after it.
// 1024 blocks = exactly 4 resident blocks/CU, no tail.
// ---------------------------------------------------------------------------
__global__ __launch_bounds__(256, 4)
void moment_final(const float* __restrict__ f_m, const float* __restrict__ f_s,
                  const float* __restrict__ A_b, const float* __restrict__ A_bT,
                  const float* __restrict__ f_b, float* __restrict__ out) {
    const int bj = blockIdx.x;
    const int b  = bj >> 7, j = bj & 127;
    const int dh = blockIdx.y;         // 0..1
    const int t  = threadIdx.x;        // 0..255
    const int c  = t & 63;             // f4 lane within d-half
    const int g  = t >> 6;             // 0..3 i-group (== wave id)

    __shared__ float w[Nc];
    __shared__ float ar[Nc];
    __shared__ __align__(16) float4 pex[3][64];

    if (t < Nc) w[t] = A_bT[bj * Nc + t];
    else        ar[t - Nc] = A_b[bj * Nc + (t - Nc)];
    __syncthreads();

    const int c4 = dh * 64 + c;        // global f4 column 0..127
    const float4 s4 = ((const float4*)(f_s + b * Dc))[c4];
    const float4 ns = make_float4(NL2E * s4.x, NL2E * s4.y, NL2E * s4.z, NL2E * s4.w);

    float4 acc  = make_float4(0.f, 0.f, 0.f, 0.f);   // moment stream
    float4 accb = make_float4(0.f, 0.f, 0.f, 0.f);   // A_b @ f_b stream
    const float4* fm4 = (const float4*)f_m;
    const float4* fb4 = (const float4*)(f_b + b * Nc * Dc);
    const long istride = (long)Nc * (Dc / 4);                  // f4: 256 KB
    long idx = ((long)(b * Nc + g * 32) * Nc + j) * (Dc / 4) + c4;
    const int mbase = g * 32;

#pragma unroll 1
    for (int ii = 0; ii < 32; ii += 8) {
        // issue the 8 HBM f_m loads first (long latency)
        float4 mv[8];
#pragma unroll
        for (int u = 0; u < 8; u++)
            mv[u] = fm4[idx + (long)u * istride];
        idx += 8 * istride;

        // hide the A_b @ f_b L2 reads under the f_m HBM latency
#pragma unroll
        for (int u = 0; u < 8; u++) {
            const float a = ar[mbase + ii + u];
            const float4 v = fb4[(mbase + ii + u) * (Dc / 4) + c4];
            accb.x = fmaf(a, v.x, accb.x); accb.y = fmaf(a, v.y, accb.y);
            accb.z = fmaf(a, v.z, accb.z); accb.w = fmaf(a, v.w, accb.w);
        }

        // consume f_m batch: gated sigmoid reduction
#pragma unroll
        for (int u = 0; u < 8; u++) {
            const float ww = w[mbase + ii + u];
            const float4 m4 = mv[u];
            acc.x = fmaf(ww * m4.x, __builtin_amdgcn_rcpf(1.f + EXP2(m4.x * ns.x)), acc.x);
            acc.y = fmaf(ww * m4.y, __builtin_amdgcn_rcpf(1.f + EXP2(m4.y * ns.y)), acc.y);
            acc.z = fmaf(ww * m4.z, __builtin_amdgcn_rcpf(1.f + EXP2(m4.z * ns.z)), acc.z);
            acc.w = fmaf(ww * m4.w, __builtin_amdgcn_rcpf(1.f + EXP2(m4.w * ns.w)), acc.w);
        }
    }

    acc.x += accb.x; acc.y += accb.y; acc.z += accb.z; acc.w += accb.w;

    if (g != 0) pex[g - 1][c] = acc;
    __syncthreads();
    if (g == 0) {
#pragma unroll
        for (int p = 0; p < 3; p++) {
            const float4 q = pex[p][c];
            acc.x += q.x; acc.y += q.y; acc.z += q.z; acc.w += q.w;
        }
        const float4 r = fb4[j * (Dc / 4) + c4];   // residual
        acc.x += r.x; acc.y += r.y; acc.z += r.z; acc.w += r.w;
        ((float4*)out)[bj * (Dc / 4) + c4] = acc;
    }
}

// ---------------------------------------------------------------------------
extern "C" void kernel_launch(void* const* d_in, const int* in_sizes, int n_in,
                              void* d_out, int out_size, void* d_ws, size_t ws_size,
                              hipStream_t stream) {
    const float* f_b = (const float*)d_in[0];
    const float* f_w = (const float*)d_in[1];
    const float* f_s = (const float*)d_in[2];
    const float* f_m = (const float*)d_in[3];
    const float* Wq  = (const float*)d_in[4];
    const float* bq  = (const float*)d_in[5];
    const float* Wk  = (const float*)d_in[6];
    const float* bk  = (const float*)d_in[7];
    float* out = (float*)d_out;

    float* ws   = (float*)d_ws;
    float* qb   = ws;                  // 4 * 512*512
    float* kb   = qb   + 4 * 512 * Dc; // 4 * 80*512
    float* f_bq = kb   + 4 * 80 * Dc;  // 512*512
    float* A_b  = f_bq + 512 * Dc;     // 512*128
    float* A_bT = A_b  + 512 * Nc;     // 512*128

    proj_gemm<<<dim3(16, 19, 4), 256, 0, stream>>>(f_b, f_w, Wq, bq, Wk, bk, qb, kb);
    cross_attn_gate<<<Bc * Nc, 256, 0, stream>>>(qb, kb, f_w, f_b, f_s, f_bq);
    self_attn_scores<<<Bc * Nc, 512, 0, stream>>>(f_bq, A_b, A_bT);
    moment_final<<<dim3(Bc * Nc, 2), 256, 0, stream>>>(f_m, f_s, A_b, A_bT, f_b, out);
}

// Round 4
// 234.092 us; speedup vs baseline: 1.0269x; 1.0269x over previous
//
#include <hip/hip_runtime.h>
#include <hip/hip_bf16.h>

// B=4, N=128, L=20, D=512
#define Bc 4
#define Nc 128
#define Lc 20
#define Dc 512
#define SCALE 0.04419417382415922f   // 1/sqrt(512)
#define NL2E -1.4426950408889634f    // -log2(e)

#if __has_builtin(__builtin_amdgcn_exp2f)
#define EXP2(x) __builtin_amdgcn_exp2f(x)
#else
#define EXP2(x) __expf((x) * 0.6931471805599453f)
#endif

// native clang vector type for nontemporal loads (HIP_vector_type is rejected)
typedef float vf4 __attribute__((ext_vector_type(4)));

#if __has_builtin(__builtin_nontemporal_load)
#define NT_LOAD4(p) __builtin_nontemporal_load((const vf4*)(p))
#else
#define NT_LOAD4(p) (*(const vf4*)(p))
#endif

// ---------------------------------------------------------------------------
// Kernel 1: q/k projections. 64x64 tiles, 4x4 micro-tile, float4 LDS
// fragments (16 FMA per 2 ds_read_b128 -> VALU-bound, not LDS-bound).
// K-split: q uses 8 parts (K=64 each, blockIdx.z=0..7), k uses 4 parts
// (K=128, z=0..3; z>=4 k-blocks exit). grid (8, 10, 8) = 576 working blocks.
// Partial outputs q[z]/k[z]; consumers sum the parts.
// ---------------------------------------------------------------------------
__global__ __launch_bounds__(256)
void proj_gemm(const float* __restrict__ f_b, const float* __restrict__ f_w,
               const float* __restrict__ Wq, const float* __restrict__ bq,
               const float* __restrict__ Wk, const float* __restrict__ bk,
               float* __restrict__ qb, float* __restrict__ kb) {
    const int t  = threadIdx.x;
    const int tc = blockIdx.x, ty = blockIdx.y, kz = blockIdx.z;
    const bool isq = ty < 8;
    if (!isq && kz >= 4) return;                 // k-part has only 4 K-splits
    const int c0    = tc * 64;
    const int r0    = isq ? ty * 64 : (ty - 8) * 64;
    const int nrows = isq ? 512 : 80;
    const int KB    = isq ? 64 : 128;            // K depth per split
    const int kbase = isq ? kz * 64 : kz * 128;
    const float* Ain  = isq ? f_b : f_w;
    const float* W    = isq ? Wq : Wk;
    const float* bias = isq ? bq : bk;           // added only in kz==0 part
    float* C          = isq ? (qb + kz * 512 * Dc) : (kb + kz * 80 * Dc);

    __shared__ __align__(16) float As[16][68];   // [k][row+pad4]
    __shared__ __align__(16) float Bs[16][68];

    // staging: thread -> (row 0..63, k-quad 0/4/8/12), one float4 per tensor
    const int srow = t >> 2;
    const int sk4  = (t & 3) * 4;
    const int arow = min(r0 + srow, nrows - 1);
    const int wrow = c0 + srow;                  // W rows = out cols, all valid

    // micro-tile: 16x16 threads, each 4 rows x 4 cols
    const int rr = (t >> 4) * 4;
    const int cc = (t & 15) * 4;
    float acc[4][4] = {};

    const float* Aptr = Ain + arow * Dc + kbase + sk4;
    const float* Wptr = W   + wrow * Dc + kbase + sk4;
    float4 ga = *(const float4*)Aptr;
    float4 gb = *(const float4*)Wptr;

    for (int kk0 = 16; kk0 <= KB; kk0 += 16) {
        __syncthreads();
        As[sk4 + 0][srow] = ga.x; As[sk4 + 1][srow] = ga.y;
        As[sk4 + 2][srow] = ga.z; As[sk4 + 3][srow] = ga.w;
        Bs[sk4 + 0][srow] = gb.x; Bs[sk4 + 1][srow] = gb.y;
        Bs[sk4 + 2][srow] = gb.z; Bs[sk4 + 3][srow] = gb.w;
        __syncthreads();
        if (kk0 < KB) {                          // prefetch next k-tile
            ga = *(const float4*)(Aptr + kk0);
            gb = *(const float4*)(Wptr + kk0);
        }
#pragma unroll
        for (int kk = 0; kk < 16; kk++) {
            const float4 av = *(const float4*)&As[kk][rr];
            const float4 bv = *(const float4*)&Bs[kk][cc];
            acc[0][0] = fmaf(av.x, bv.x, acc[0][0]);
            acc[0][1] = fmaf(av.x, bv.y, acc[0][1]);
            acc[0][2] = fmaf(av.x, bv.z, acc[0][2]);
            acc[0][3] = fmaf(av.x, bv.w, acc[0][3]);
            acc[1][0] = fmaf(av.y, bv.x, acc[1][0]);
            acc[1][1] = fmaf(av.y, bv.y, acc[1][1]);
            acc[1][2] = fmaf(av.y, bv.z, acc[1][2]);
            acc[1][3] = fmaf(av.y, bv.w, acc[1][3]);
            acc[2][0] = fmaf(av.z, bv.x, acc[2][0]);
            acc[2][1] = fmaf(av.z, bv.y, acc[2][1]);
            acc[2][2] = fmaf(av.z, bv.z, acc[2][2]);
            acc[2][3] = fmaf(av.z, bv.w, acc[2][3]);
            acc[3][0] = fmaf(av.w, bv.x, acc[3][0]);
            acc[3][1] = fmaf(av.w, bv.y, acc[3][1]);
            acc[3][2] = fmaf(av.w, bv.z, acc[3][2]);
            acc[3][3] = fmaf(av.w, bv.w, acc[3][3]);
        }
    }

    float4 bv4 = make_float4(0.f, 0.f, 0.f, 0.f);
    if (kz == 0) bv4 = *(const float4*)&bias[c0 + cc];
#pragma unroll
    for (int i = 0; i < 4; i++) {
        const int orow = r0 + rr + i;
        if (orow < nrows) {
            float4 o;
            o.x = acc[i][0] + bv4.x; o.y = acc[i][1] + bv4.y;
            o.z = acc[i][2] + bv4.z; o.w = acc[i][3] + bv4.w;
            *(float4*)&C[orow * Dc + c0 + cc] = o;
        }
    }
}

// ---------------------------------------------------------------------------
// Kernel 2: cross-attention over L=20 + sentence gate -> f_bq
// (sums the 8 K-split parts of q and 4 parts of k at load)
// ---------------------------------------------------------------------------
__global__ __launch_bounds__(256)
void cross_attn_gate(const float* __restrict__ qb, const float* __restrict__ kb,
                     const float* __restrict__ f_w, const float* __restrict__ f_b,
                     const float* __restrict__ f_s, float* __restrict__ f_bq) {
    const int bn = blockIdx.x;
    const int b  = bn >> 7;
    const int t  = threadIdx.x;
    const int lane = t & 63, wave = t >> 6;

    __shared__ __align__(16) float qs[Dc];
    __shared__ float sc[32];
    __shared__ float invs;

    {
        float2 s = make_float2(0.f, 0.f);
#pragma unroll
        for (int h = 0; h < 8; h++) {
            const float2 u = ((const float2*)(qb + h * 512 * Dc + bn * Dc))[t];
            s.x += u.x; s.y += u.y;
        }
        ((float2*)qs)[t] = s;
    }
    __syncthreads();

    const float4* q4 = (const float4*)qs;
    const float4 qa = q4[lane];
    const float4 qv = q4[lane + 64];

    for (int l = wave; l < Lc; l += 4) {
        float4 ka = make_float4(0.f, 0.f, 0.f, 0.f);
        float4 kv = make_float4(0.f, 0.f, 0.f, 0.f);
#pragma unroll
        for (int h = 0; h < 4; h++) {
            const float4* kr = (const float4*)(kb + h * 80 * Dc + (b * Lc + l) * Dc);
            const float4 u = kr[lane];
            const float4 v = kr[lane + 64];
            ka.x += u.x; ka.y += u.y; ka.z += u.z; ka.w += u.w;
            kv.x += v.x; kv.y += v.y; kv.z += v.z; kv.w += v.w;
        }
        float s = qa.x * ka.x + qa.y * ka.y + qa.z * ka.z + qa.w * ka.w
                + qv.x * kv.x + qv.y * kv.y + qv.z * kv.z + qv.w * kv.w;
#pragma unroll
        for (int d = 32; d >= 1; d >>= 1) s += __shfl_down(s, d, 64);
        if (lane == 0) sc[l] = s * SCALE;
    }
    __syncthreads();

    if (t == 0) {
        float mx = sc[0];
        for (int l = 1; l < Lc; l++) mx = fmaxf(mx, sc[l]);
        float sum = 0.f;
        for (int l = 0; l < Lc; l++) { float e = __expf(sc[l] - mx); sc[l] = e; sum += e; }
        invs = 1.0f / sum;
    }
    __syncthreads();
    const float inv = invs;

    const float2* fw2 = (const float2*)(f_w + b * Lc * Dc);
    float2 acc = make_float2(0.f, 0.f);
#pragma unroll 5
    for (int l = 0; l < Lc; l++) {
        const float2 v = fw2[l * 256 + t];
        const float w = sc[l];
        acc.x = fmaf(w, v.x, acc.x);
        acc.y = fmaf(w, v.y, acc.y);
    }
    const float2 s2 = ((const float2*)(f_s + b * Dc))[t];
    const float2 fb2 = ((const float2*)(f_b + bn * Dc))[t];
    float2 o;
    o.x = fb2.x * (acc.x * inv + s2.x);
    o.y = fb2.y * (acc.y * inv + s2.y);
    ((float2*)(f_bq + bn * Dc))[t] = o;
}

// ---------------------------------------------------------------------------
// Kernel 3: A_b / A_bT softmax rows. 512 threads (8 waves).
// Reductions over the 128 scores via per-wave shuffle butterflies.
// ---------------------------------------------------------------------------
__global__ __launch_bounds__(512)
void self_attn_scores(const float* __restrict__ f_bq,
                      float* __restrict__ A_b, float* __restrict__ A_bT) {
    const int bn = blockIdx.x;
    const int b  = bn >> 7, n = bn & 127;
    const int t  = threadIdx.x;          // 0..511
    const int lane = t & 63, wave = t >> 6;   // 8 waves

    __shared__ __align__(16) float qrow[Dc];
    __shared__ float sc[Nc];
    __shared__ float redm[2];
    __shared__ float reds[2];

    qrow[t] = f_bq[bn * Dc + t];
    __syncthreads();

    const float4* q4 = (const float4*)qrow;
    const float4 qa = q4[lane];
    const float4 qv = q4[lane + 64];

    for (int m = wave; m < Nc; m += 8) {
        const float4* kr = (const float4*)(f_bq + (b * Nc + m) * Dc);
        const float4 va = kr[lane];
        const float4 vb = kr[lane + 64];
        float s = qa.x * va.x + qa.y * va.y + qa.z * va.z + qa.w * va.w
                + qv.x * vb.x + qv.y * vb.y + qv.z * vb.z + qv.w * vb.w;
#pragma unroll
        for (int d = 32; d >= 1; d >>= 1) s += __shfl_down(s, d, 64);
        if (lane == 0) sc[m] = s * SCALE;
    }
    __syncthreads();

    float sval = 0.f, e = 0.f;
    if (t < Nc) {                         // waves 0 and 1 exactly
        sval = sc[t];
        float m = sval;
#pragma unroll
        for (int d = 32; d >= 1; d >>= 1) m = fmaxf(m, __shfl_xor(m, d, 64));
        if (lane == 0) redm[wave] = m;
    }
    __syncthreads();
    if (t < Nc) {
        const float mx = fmaxf(redm[0], redm[1]);
        e = __expf(sval - mx);
        float s = e;
#pragma unroll
        for (int d = 32; d >= 1; d >>= 1) s += __shfl_xor(s, d, 64);
        if (lane == 0) reds[wave] = s;
    }
    __syncthreads();
    if (t < Nc) {
        const float a = e * (1.0f / (reds[0] + reds[1]));
        A_b[bn * Nc + t] = a;
        A_bT[(b * Nc + t) * Nc + n] = a;
    }
}

// ---------------------------------------------------------------------------
// Kernel 4: fused moment reduction + self-attn apply + residual.
// (round-2 best-measured form: nt f_m loads, batch-8 in flight,
//  f_b pass after the stream loop.)
// grid (512, 2): blockIdx.x = (b,j), blockIdx.y = d-HALF (64 float4).
// 1024 blocks = exactly 4 resident blocks/CU, no tail.
// ---------------------------------------------------------------------------
__global__ __launch_bounds__(256, 4)
void moment_final(const float* __restrict__ f_m, const float* __restrict__ f_s,
                  const float* __restrict__ A_b, const float* __restrict__ A_bT,
                  const float* __restrict__ f_b, float* __restrict__ out) {
    const int bj = blockIdx.x;
    const int b  = bj >> 7, j = bj & 127;
    const int dh = blockIdx.y;         // 0..1
    const int t  = threadIdx.x;        // 0..255
    const int c  = t & 63;             // f4 lane within d-half
    const int g  = t >> 6;             // 0..3 i-group (== wave id)

    __shared__ float w[Nc];
    __shared__ float ar[Nc];
    __shared__ __align__(16) float4 pex[3][64];

    if (t < Nc) w[t] = A_bT[bj * Nc + t];
    else        ar[t - Nc] = A_b[bj * Nc + (t - Nc)];
    __syncthreads();

    const int c4 = dh * 64 + c;        // global f4 column 0..127
    const float4 s4 = ((const float4*)(f_s + b * Dc))[c4];
    const float4 ns = make_float4(NL2E * s4.x, NL2E * s4.y, NL2E * s4.z, NL2E * s4.w);

    float4 acc = make_float4(0.f, 0.f, 0.f, 0.f);
    const float* fm = f_m;
    const long istride = (long)Nc * Dc;                        // floats: 256 KB
    long idx = ((long)(b * Nc + g * 32) * Nc + j) * Dc + c4 * 4;

#pragma unroll 1
    for (int ii = 0; ii < 32; ii += 8) {
        vf4 mv[8];
#pragma unroll
        for (int u = 0; u < 8; u++)
            mv[u] = NT_LOAD4(fm + idx + (long)u * istride);
        idx += 8 * istride;
#pragma unroll
        for (int u = 0; u < 8; u++) {
            const float ww = w[g * 32 + ii + u];
            const vf4 m4 = mv[u];
            acc.x = fmaf(ww * m4.x, __builtin_amdgcn_rcpf(1.f + EXP2(m4.x * ns.x)), acc.x);
            acc.y = fmaf(ww * m4.y, __builtin_amdgcn_rcpf(1.f + EXP2(m4.y * ns.y)), acc.y);
            acc.z = fmaf(ww * m4.z, __builtin_amdgcn_rcpf(1.f + EXP2(m4.z * ns.z)), acc.z);
            acc.w = fmaf(ww * m4.w, __builtin_amdgcn_rcpf(1.f + EXP2(m4.w * ns.w)), acc.w);
        }
    }

    const float4* fb4 = (const float4*)(f_b + b * Nc * Dc);
    const int mbase = g * 32;
#pragma unroll 4
    for (int m = mbase; m < mbase + 32; m++) {
        const float a = ar[m];
        const float4 v = fb4[m * (Dc / 4) + c4];
        acc.x = fmaf(a, v.x, acc.x); acc.y = fmaf(a, v.y, acc.y);
        acc.z = fmaf(a, v.z, acc.z); acc.w = fmaf(a, v.w, acc.w);
    }

    if (g != 0) pex[g - 1][c] = acc;
    __syncthreads();
    if (g == 0) {
#pragma unroll
        for (int p = 0; p < 3; p++) {
            const float4 q = pex[p][c];
            acc.x += q.x; acc.y += q.y; acc.z += q.z; acc.w += q.w;
        }
        const float4 r = fb4[j * (Dc / 4) + c4];   // residual
        acc.x += r.x; acc.y += r.y; acc.z += r.z; acc.w += r.w;
        ((float4*)out)[bj * (Dc / 4) + c4] = acc;
    }
}

// ---------------------------------------------------------------------------
extern "C" void kernel_launch(void* const* d_in, const int* in_sizes, int n_in,
                              void* d_out, int out_size, void* d_ws, size_t ws_size,
                              hipStream_t stream) {
    const float* f_b = (const float*)d_in[0];
    const float* f_w = (const float*)d_in[1];
    const float* f_s = (const float*)d_in[2];
    const float* f_m = (const float*)d_in[3];
    const float* Wq  = (const float*)d_in[4];
    const float* bq  = (const float*)d_in[5];
    const float* Wk  = (const float*)d_in[6];
    const float* bk  = (const float*)d_in[7];
    float* out = (float*)d_out;

    float* ws   = (float*)d_ws;
    float* qb   = ws;                  // 8 * 512*512
    float* kb   = qb   + 8 * 512 * Dc; // 4 * 80*512
    float* f_bq = kb   + 4 * 80 * Dc;  // 512*512
    float* A_b  = f_bq + 512 * Dc;     // 512*128
    float* A_bT = A_b  + 512 * Nc;     // 512*128

    proj_gemm<<<dim3(8, 10, 8), 256, 0, stream>>>(f_b, f_w, Wq, bq, Wk, bk, qb, kb);
    cross_attn_gate<<<Bc * Nc, 256, 0, stream>>>(qb, kb, f_w, f_b, f_s, f_bq);
    self_attn_scores<<<Bc * Nc, 512, 0, stream>>>(f_bq, A_b, A_bT);
    moment_final<<<dim3(Bc * Nc, 2), 256, 0, stream>>>(f_m, f_s, A_b, A_bT, f_b, out);
}